// Round 7
// baseline (460.900 us; speedup 1.0000x reference)
//
#include <hip/hip_runtime.h>

#define NPTS  262144
#define NV    6890
#define NVP   6896          // padded to multiple of 8
#define NJ    24
#define TILE  3448          // NVP/2 verts per LDS tile (55.2 KB)
#define NTILE 2
#define PPL   4             // points per lane
#define WGS   256
#define NWG   (NPTS / (WGS * PPL))   // 256

// Pack verts as [-2x, -2y, -2z, |v|^2]: d~ = |v|^2 - 2 q.v (argmin-equivalent).
// |v|^2 in numpy's rounding order: (x*x + y*y) + z*z.
__global__ void pack_verts_kernel(const float* __restrict__ verts, float4* __restrict__ vp) {
    int v = blockIdx.x * 256 + threadIdx.x;
    if (v >= NVP) return;
    if (v < NV) {
        float x = verts[3*v+0], y = verts[3*v+1], z = verts[3*v+2];
        float vs = __fadd_rn(__fadd_rn(__fmul_rn(x,x), __fmul_rn(y,y)), __fmul_rn(z,z));
        vp[v] = make_float4(-2.f*x, -2.f*y, -2.f*z, vs);
    } else {
        vp[v] = make_float4(0.f, 0.f, 0.f, 3.0e37f);  // pad: never selected
    }
}

template<int PACKED>
__global__ __launch_bounds__(WGS)
void knn_blend_kernel(const float* __restrict__ qpts,
                      const float4* __restrict__ vp,
                      const float* __restrict__ verts,
                      const float* __restrict__ weights,
                      const float* __restrict__ At,
                      const float* __restrict__ Ab,
                      float* __restrict__ out)
{
    __shared__ float4 sv[TILE];
    __shared__ float  sAt[NJ*16];
    __shared__ float  sAb[NJ*16];
    const int tid = threadIdx.x;
    for (int i = tid; i < NJ*16; i += WGS) { sAt[i] = At[i]; sAb[i] = Ab[i]; }

    if (PACKED) {
        // 4 points per lane: point p lives at blk*1024 + p*256 + tid (coalesced)
        const int n0 = blockIdx.x * (WGS * PPL) + tid;
        float q0[PPL], q1[PPL], q2[PPL];
#pragma unroll
        for (int p = 0; p < PPL; ++p) {
            const int n = n0 + p * WGS;
            q0[p] = qpts[3*n+0]; q1[p] = qpts[3*n+1]; q2[p] = qpts[3*n+2];
        }
        float best[PPL]; int bi[PPL];
#pragma unroll
        for (int p = 0; p < PPL; ++p) { best[p] = 3.4e38f; bi[p] = 0; }

        for (int t = 0; t < NTILE; ++t) {
            const int tb = t * TILE;
            __syncthreads();                        // previous-tile readers done
            for (int i = tid; i < TILE; i += WGS)   // cooperative stage, float4
                sv[i] = vp[tb + i];
            __syncthreads();
#pragma unroll 8
            for (int u = 0; u < TILE; ++u) {
                const float4 vv = sv[u];            // wave-uniform -> broadcast
                const int cand = tb + u;            // uniform -> SALU
#pragma unroll
                for (int p = 0; p < PPL; ++p) {
                    // same fma-chain order as the round-5 passing kernel
                    const float d = fmaf(vv.x, q0[p], fmaf(vv.y, q1[p], fmaf(vv.z, q2[p], vv.w)));
                    const bool lt = d < best[p];    // strict < = first-occurrence argmin
                    best[p] = lt ? d : best[p];
                    bi[p]   = lt ? cand : bi[p];
                }
            }
        }

        // Epilogue: per point, gather weights, blend, invert, transform, store.
#pragma unroll
        for (int p = 0; p < PPL; ++p) {
            const int n = n0 + p * WGS;
            const float* wrow = weights + bi[p] * NJ;
            float M1[12], M2[12];
#pragma unroll
            for (int i = 0; i < 12; ++i) { M1[i] = 0.f; M2[i] = 0.f; }
            for (int k = 0; k < NJ; ++k) {
                const float w = wrow[k];
                const float* a = sAt + k*16;
                const float* b = sAb + k*16;
#pragma unroll
                for (int i = 0; i < 12; ++i) {
                    M1[i] = fmaf(w, a[i], M1[i]);
                    M2[i] = fmaf(w, b[i], M2[i]);
                }
            }
            float p0 = q0[p] - M1[3], p1 = q1[p] - M1[7], p2 = q2[p] - M1[11];
            float a_=M1[0], b_=M1[1], c_=M1[2];
            float d_=M1[4], e_=M1[5], f_=M1[6];
            float g_=M1[8], h_=M1[9], i_=M1[10];
            float A0 = e_*i_ - f_*h_, A1 = c_*h_ - b_*i_, A2 = b_*f_ - c_*e_;
            float A3 = f_*g_ - d_*i_, A4 = a_*i_ - c_*g_, A5 = c_*d_ - a_*f_;
            float A6 = d_*h_ - e_*g_, A7 = b_*g_ - a_*h_, A8 = a_*e_ - b_*d_;
            float det  = a_*A0 + b_*A3 + c_*A6;
            float rdet = 1.0f / det;
            float x0 = (A0*p0 + A1*p1 + A2*p2) * rdet;
            float x1 = (A3*p0 + A4*p1 + A5*p2) * rdet;
            float x2 = (A6*p0 + A7*p1 + A8*p2) * rdet;
            out[3*n+0] = fmaf(M2[0],x0, fmaf(M2[1],x1, fmaf(M2[2], x2, M2[3])));
            out[3*n+1] = fmaf(M2[4],x0, fmaf(M2[5],x1, fmaf(M2[6], x2, M2[7])));
            out[3*n+2] = fmaf(M2[8],x0, fmaf(M2[9],x1, fmaf(M2[10],x2, M2[11])));
        }
    } else {
        // fallback (no workspace): 1 point per lane, direct scan, reference-shaped rounding
        const int n = blockIdx.x * WGS + tid;
        if (n >= NPTS) return;
        const float q0 = qpts[3*n+0], q1 = qpts[3*n+1], q2 = qpts[3*n+2];
        const float qsq = __fadd_rn(__fadd_rn(__fmul_rn(q0,q0), __fmul_rn(q1,q1)), __fmul_rn(q2,q2));
        float best = 3.4e38f; int bi = 0;
        for (int v = 0; v < NV; ++v) {
            float vx = verts[3*v+0], vy = verts[3*v+1], vz = verts[3*v+2];
            float vs = __fadd_rn(__fadd_rn(__fmul_rn(vx,vx), __fmul_rn(vy,vy)), __fmul_rn(vz,vz));
            float tq = fmaf(q2, vz, fmaf(q1, vy, __fmul_rn(q0, vx)));
            float d  = __fadd_rn(__fsub_rn(qsq, __fadd_rn(tq, tq)), vs);
            bool lt = d < best;
            best = lt ? d : best;
            bi   = lt ? v : bi;
        }
        __syncthreads();
        const float* wrow = weights + bi * NJ;
        float M1[12], M2[12];
#pragma unroll
        for (int i = 0; i < 12; ++i) { M1[i] = 0.f; M2[i] = 0.f; }
        for (int k = 0; k < NJ; ++k) {
            const float w = wrow[k];
            const float* a = sAt + k*16;
            const float* b = sAb + k*16;
#pragma unroll
            for (int i = 0; i < 12; ++i) {
                M1[i] = fmaf(w, a[i], M1[i]);
                M2[i] = fmaf(w, b[i], M2[i]);
            }
        }
        float p0 = q0 - M1[3], p1 = q1 - M1[7], p2 = q2 - M1[11];
        float a_=M1[0], b_=M1[1], c_=M1[2];
        float d_=M1[4], e_=M1[5], f_=M1[6];
        float g_=M1[8], h_=M1[9], i_=M1[10];
        float A0 = e_*i_ - f_*h_, A1 = c_*h_ - b_*i_, A2 = b_*f_ - c_*e_;
        float A3 = f_*g_ - d_*i_, A4 = a_*i_ - c_*g_, A5 = c_*d_ - a_*f_;
        float A6 = d_*h_ - e_*g_, A7 = b_*g_ - a_*h_, A8 = a_*e_ - b_*d_;
        float det  = a_*A0 + b_*A3 + c_*A6;
        float rdet = 1.0f / det;
        float x0 = (A0*p0 + A1*p1 + A2*p2) * rdet;
        float x1 = (A3*p0 + A4*p1 + A5*p2) * rdet;
        float x2 = (A6*p0 + A7*p1 + A8*p2) * rdet;
        out[3*n+0] = fmaf(M2[0],x0, fmaf(M2[1],x1, fmaf(M2[2], x2, M2[3])));
        out[3*n+1] = fmaf(M2[4],x0, fmaf(M2[5],x1, fmaf(M2[6], x2, M2[7])));
        out[3*n+2] = fmaf(M2[8],x0, fmaf(M2[9],x1, fmaf(M2[10],x2, M2[11])));
    }
}

extern "C" void kernel_launch(void* const* d_in, const int* in_sizes, int n_in,
                              void* d_out, int out_size, void* d_ws, size_t ws_size,
                              hipStream_t stream) {
    const float* qpts    = (const float*)d_in[0];
    const float* verts   = (const float*)d_in[1];
    const float* weights = (const float*)d_in[2];
    const float* At      = (const float*)d_in[3];
    const float* Ab      = (const float*)d_in[4];
    float* out = (float*)d_out;

    const size_t need = (size_t)NVP * sizeof(float4);
    if (ws_size >= need) {
        float4* vp = (float4*)d_ws;
        pack_verts_kernel<<<(NVP + 255) / 256, 256, 0, stream>>>(verts, vp);
        knn_blend_kernel<1><<<NWG, WGS, 0, stream>>>(qpts, vp, verts, weights, At, Ab, out);
    } else {
        knn_blend_kernel<0><<<(NPTS + WGS - 1) / WGS, WGS, 0, stream>>>(qpts, nullptr, verts, weights, At, Ab, out);
    }
}

// Round 9
// 386.832 us; speedup vs baseline: 1.1915x; 1.1915x over previous
//
#include <hip/hip_runtime.h>

#define NPTS  262144
#define NV    6890
#define NVP   6896          // padded to multiple of 8
#define NJ    24
#define TILE  3448          // NVP/2 verts per LDS tile (55.2 KB)
#define NTILE 2
#define PPL   4             // points per lane
#define WGS   256
#define NWG   (NPTS / (WGS * PPL))   // 256 = one WG per CU

// Pack verts as [-2x, -2y, -2z, |v|^2]: d~ = |v|^2 - 2 q.v (argmin-equivalent).
// |v|^2 in numpy's rounding order: (x*x + y*y) + z*z.
__global__ void pack_verts_kernel(const float* __restrict__ verts, float4* __restrict__ vp) {
    int v = blockIdx.x * 256 + threadIdx.x;
    if (v >= NVP) return;
    if (v < NV) {
        float x = verts[3*v+0], y = verts[3*v+1], z = verts[3*v+2];
        float vs = __fadd_rn(__fadd_rn(__fmul_rn(x,x), __fmul_rn(y,y)), __fmul_rn(z,z));
        vp[v] = make_float4(-2.f*x, -2.f*y, -2.f*z, vs);
    } else {
        vp[v] = make_float4(0.f, 0.f, 0.f, 3.0e37f);  // pad: never selected
    }
}

// Kernel A: KNN only. PPL=4 points per lane; vertex stream broadcast from LDS.
// Tiny register footprint (no epilogue) -> no spills.
__global__ __launch_bounds__(WGS)
void knn_kernel(const float* __restrict__ qpts,
                const float4* __restrict__ vp,
                int* __restrict__ bidx)
{
    __shared__ float4 sv[TILE];
    const int tid = threadIdx.x;
    const int n0 = blockIdx.x * (WGS * PPL) + tid;

    float q0[PPL], q1[PPL], q2[PPL];
#pragma unroll
    for (int p = 0; p < PPL; ++p) {
        const int n = n0 + p * WGS;           // coalesced: lane i -> point base+i
        q0[p] = qpts[3*n+0]; q1[p] = qpts[3*n+1]; q2[p] = qpts[3*n+2];
    }
    float best[PPL]; int bi[PPL];
#pragma unroll
    for (int p = 0; p < PPL; ++p) { best[p] = 3.4e38f; bi[p] = 0; }

    for (int t = 0; t < NTILE; ++t) {
        const int tb = t * TILE;
        __syncthreads();                       // previous-tile readers done
        for (int i = tid; i < TILE; i += WGS)  // cooperative stage, float4
            sv[i] = vp[tb + i];
        __syncthreads();
#pragma unroll 8
        for (int u = 0; u < TILE; ++u) {
            const float4 vv = sv[u];           // wave-uniform -> broadcast
            const int cand = tb + u;           // uniform -> SALU
#pragma unroll
            for (int p = 0; p < PPL; ++p) {
                // same fma-chain order as the round-5 passing kernel
                const float d = fmaf(vv.x, q0[p], fmaf(vv.y, q1[p], fmaf(vv.z, q2[p], vv.w)));
                const bool lt = d < best[p];   // strict < = first-occurrence argmin
                best[p] = lt ? d : best[p];
                bi[p]   = lt ? cand : bi[p];
            }
        }
    }
#pragma unroll
    for (int p = 0; p < PPL; ++p)
        bidx[n0 + p * WGS] = bi[p];            // coalesced int stores
}

// Kernel B: blend/inverse/transform epilogue, 1 point per thread, full occupancy.
template<int HAVE_IDX>
__global__ __launch_bounds__(256)
void blend_kernel(const float* __restrict__ qpts,
                  const float* __restrict__ verts,
                  const float* __restrict__ weights,
                  const float* __restrict__ At,
                  const float* __restrict__ Ab,
                  const int* __restrict__ bidx,
                  float* __restrict__ out)
{
    __shared__ float sAt[NJ*16];
    __shared__ float sAb[NJ*16];
    const int tid = threadIdx.x;
    for (int i = tid; i < NJ*16; i += 256) { sAt[i] = At[i]; sAb[i] = Ab[i]; }

    const int n = blockIdx.x * 256 + tid;
    const float q0 = qpts[3*n+0], q1 = qpts[3*n+1], q2 = qpts[3*n+2];

    int bi;
    if (HAVE_IDX) {
        bi = bidx[n];
        __syncthreads();
    } else {
        // fallback: direct scan, reference-shaped rounding
        const float qsq = __fadd_rn(__fadd_rn(__fmul_rn(q0,q0), __fmul_rn(q1,q1)), __fmul_rn(q2,q2));
        float best = 3.4e38f; bi = 0;
        for (int v = 0; v < NV; ++v) {
            float vx = verts[3*v+0], vy = verts[3*v+1], vz = verts[3*v+2];
            float vs = __fadd_rn(__fadd_rn(__fmul_rn(vx,vx), __fmul_rn(vy,vy)), __fmul_rn(vz,vz));
            float tq = fmaf(q2, vz, fmaf(q1, vy, __fmul_rn(q0, vx)));
            float d  = __fadd_rn(__fsub_rn(qsq, __fadd_rn(tq, tq)), vs);
            bool lt = d < best;
            best = lt ? d : best;
            bi   = lt ? v : bi;
        }
        __syncthreads();
    }

    // weights row: 24 floats = 6 x float4 (rows are 96B, 16B-aligned)
    const float4* wrow4 = (const float4*)(weights + (size_t)bi * NJ);
    float wv[NJ];
#pragma unroll
    for (int j = 0; j < 6; ++j) {
        float4 w4 = wrow4[j];
        wv[4*j+0] = w4.x; wv[4*j+1] = w4.y; wv[4*j+2] = w4.z; wv[4*j+3] = w4.w;
    }

    float M1[12], M2[12];
#pragma unroll
    for (int i = 0; i < 12; ++i) { M1[i] = 0.f; M2[i] = 0.f; }
#pragma unroll
    for (int k = 0; k < NJ; ++k) {
        const float w = wv[k];
        const float* a = sAt + k*16;
        const float* b = sAb + k*16;
#pragma unroll
        for (int i = 0; i < 12; ++i) {
            M1[i] = fmaf(w, a[i], M1[i]);
            M2[i] = fmaf(w, b[i], M2[i]);
        }
    }

    // can = inv(M1[:3,:3]) @ (q - M1[:,3])  via adjugate/det (well-conditioned)
    float p0 = q0 - M1[3], p1 = q1 - M1[7], p2 = q2 - M1[11];
    float a_=M1[0], b_=M1[1], c_=M1[2];
    float d_=M1[4], e_=M1[5], f_=M1[6];
    float g_=M1[8], h_=M1[9], i_=M1[10];
    float A0 = e_*i_ - f_*h_, A1 = c_*h_ - b_*i_, A2 = b_*f_ - c_*e_;
    float A3 = f_*g_ - d_*i_, A4 = a_*i_ - c_*g_, A5 = c_*d_ - a_*f_;
    float A6 = d_*h_ - e_*g_, A7 = b_*g_ - a_*h_, A8 = a_*e_ - b_*d_;
    float det  = a_*A0 + b_*A3 + c_*A6;
    float rdet = 1.0f / det;
    float x0 = (A0*p0 + A1*p1 + A2*p2) * rdet;
    float x1 = (A3*p0 + A4*p1 + A5*p2) * rdet;
    float x2 = (A6*p0 + A7*p1 + A8*p2) * rdet;

    // out = M2[:3,:3] @ can + M2[:,3]
    out[3*n+0] = fmaf(M2[0],x0, fmaf(M2[1],x1, fmaf(M2[2], x2, M2[3])));
    out[3*n+1] = fmaf(M2[4],x0, fmaf(M2[5],x1, fmaf(M2[6], x2, M2[7])));
    out[3*n+2] = fmaf(M2[8],x0, fmaf(M2[9],x1, fmaf(M2[10],x2, M2[11])));
}

extern "C" void kernel_launch(void* const* d_in, const int* in_sizes, int n_in,
                              void* d_out, int out_size, void* d_ws, size_t ws_size,
                              hipStream_t stream) {
    const float* qpts    = (const float*)d_in[0];
    const float* verts   = (const float*)d_in[1];
    const float* weights = (const float*)d_in[2];
    const float* At      = (const float*)d_in[3];
    const float* Ab      = (const float*)d_in[4];
    float* out = (float*)d_out;

    const size_t vp_bytes = (size_t)NVP * sizeof(float4);
    const size_t need = vp_bytes + (size_t)NPTS * sizeof(int);
    if (ws_size >= need) {
        float4* vp = (float4*)d_ws;
        int* bidx  = (int*)((char*)d_ws + vp_bytes);
        pack_verts_kernel<<<(NVP + 255) / 256, 256, 0, stream>>>(verts, vp);
        knn_kernel<<<NWG, WGS, 0, stream>>>(qpts, vp, bidx);
        blend_kernel<1><<<NPTS / 256, 256, 0, stream>>>(qpts, verts, weights, At, Ab, bidx, out);
    } else {
        blend_kernel<0><<<NPTS / 256, 256, 0, stream>>>(qpts, verts, weights, At, Ab, nullptr, out);
    }
}

// Round 10
// 315.881 us; speedup vs baseline: 1.4591x; 1.2246x over previous
//
#include <hip/hip_runtime.h>

#define NPTS    262144
#define NV      6890
#define NCHUNK  4
#define CHUNKV  1728                 // verts per chunk (8-aligned), 4*1728 = 6912
#define NVP     (NCHUNK * CHUNKV)    // padded vertex count
#define NJ      24
#define PPL     4                    // points per lane
#define WGS     256
#define NPG     (NPTS / (WGS * PPL)) // 256 point-groups
#define NWG     (NPG * NCHUNK)       // 1024 WGs = 4 per CU

// Pack verts as [-2x, -2y, -2z, |v|^2]: d~ = |v|^2 - 2 q.v (argmin-equivalent).
// |v|^2 in numpy's rounding order: (x*x + y*y) + z*z.
__global__ void pack_verts_kernel(const float* __restrict__ verts, float4* __restrict__ vp) {
    int v = blockIdx.x * 256 + threadIdx.x;
    if (v >= NVP) return;
    if (v < NV) {
        float x = verts[3*v+0], y = verts[3*v+1], z = verts[3*v+2];
        float vs = __fadd_rn(__fadd_rn(__fmul_rn(x,x), __fmul_rn(y,y)), __fmul_rn(z,z));
        vp[v] = make_float4(-2.f*x, -2.f*y, -2.f*z, vs);
    } else {
        vp[v] = make_float4(0.f, 0.f, 0.f, 3.0e37f);  // pad: never selected
    }
}

// Kernel A: split-K KNN. Each WG scans ONE 1728-vert chunk for 1024 points
// (PPL=4). 4 chunk-WGs per point-group -> 4 WGs/CU -> 4 waves/SIMD for
// latency hiding. Partial (best, idx) per chunk written to workspace.
__global__ __launch_bounds__(WGS, 4)
void knn_kernel(const float* __restrict__ qpts,
                const float4* __restrict__ vp,
                float* __restrict__ bestp,
                int*   __restrict__ idxp)
{
    __shared__ float4 sv[CHUNKV];
    const int tid   = threadIdx.x;
    const int wg    = blockIdx.x;
    const int chunk = wg & (NCHUNK - 1);
    const int pg    = wg >> 2;
    const int vbase = chunk * CHUNKV;
    const int n0    = pg * (WGS * PPL) + tid;

    // stage this WG's chunk (27.6 KB)
    for (int i = tid; i < CHUNKV; i += WGS)
        sv[i] = vp[vbase + i];

    float q0[PPL], q1[PPL], q2[PPL];
#pragma unroll
    for (int p = 0; p < PPL; ++p) {
        const int n = n0 + p * WGS;            // coalesced
        q0[p] = qpts[3*n+0]; q1[p] = qpts[3*n+1]; q2[p] = qpts[3*n+2];
    }
    float best[PPL]; int bi[PPL];
#pragma unroll
    for (int p = 0; p < PPL; ++p) { best[p] = 3.4e38f; bi[p] = vbase; }

    __syncthreads();

#pragma unroll 8
    for (int u = 0; u < CHUNKV; ++u) {
        const float4 vv = sv[u];               // wave-uniform -> broadcast
        const int cand = vbase + u;            // uniform -> SALU
#pragma unroll
        for (int p = 0; p < PPL; ++p) {
            // same fma-chain order as the round-5/9 passing kernels
            const float d = fmaf(vv.x, q0[p], fmaf(vv.y, q1[p], fmaf(vv.z, q2[p], vv.w)));
            const bool lt = d < best[p];       // strict < = first-occurrence argmin
            best[p] = lt ? d : best[p];
            bi[p]   = lt ? cand : bi[p];
        }
    }

#pragma unroll
    for (int p = 0; p < PPL; ++p) {
        const int n = n0 + p * WGS;
        bestp[(size_t)chunk * NPTS + n] = best[p];   // coalesced
        idxp [(size_t)chunk * NPTS + n] = bi[p];
    }
}

// Kernel B: merge 4 chunk-partials, then blend/inverse/transform epilogue.
template<int HAVE_IDX>
__global__ __launch_bounds__(256)
void blend_kernel(const float* __restrict__ qpts,
                  const float* __restrict__ verts,
                  const float* __restrict__ weights,
                  const float* __restrict__ At,
                  const float* __restrict__ Ab,
                  const float* __restrict__ bestp,
                  const int*   __restrict__ idxp,
                  float* __restrict__ out)
{
    __shared__ float sAt[NJ*16];
    __shared__ float sAb[NJ*16];
    const int tid = threadIdx.x;
    for (int i = tid; i < NJ*16; i += 256) { sAt[i] = At[i]; sAb[i] = Ab[i]; }

    const int n = blockIdx.x * 256 + tid;
    const float q0 = qpts[3*n+0], q1 = qpts[3*n+1], q2 = qpts[3*n+2];

    int bi;
    if (HAVE_IDX) {
        // merge partials; chunks are ascending index ranges, so strict <
        // preserves numpy first-occurrence tie-breaking
        float bb = bestp[n];
        bi = idxp[n];
#pragma unroll
        for (int c = 1; c < NCHUNK; ++c) {
            const float bc = bestp[(size_t)c * NPTS + n];
            const int   ic = idxp [(size_t)c * NPTS + n];
            const bool lt = bc < bb;
            bb = lt ? bc : bb;
            bi = lt ? ic : bi;
        }
        __syncthreads();
    } else {
        // fallback: direct scan, reference-shaped rounding
        const float qsq = __fadd_rn(__fadd_rn(__fmul_rn(q0,q0), __fmul_rn(q1,q1)), __fmul_rn(q2,q2));
        float best = 3.4e38f; bi = 0;
        for (int v = 0; v < NV; ++v) {
            float vx = verts[3*v+0], vy = verts[3*v+1], vz = verts[3*v+2];
            float vs = __fadd_rn(__fadd_rn(__fmul_rn(vx,vx), __fmul_rn(vy,vy)), __fmul_rn(vz,vz));
            float tq = fmaf(q2, vz, fmaf(q1, vy, __fmul_rn(q0, vx)));
            float d  = __fadd_rn(__fsub_rn(qsq, __fadd_rn(tq, tq)), vs);
            bool lt = d < best;
            best = lt ? d : best;
            bi   = lt ? v : bi;
        }
        __syncthreads();
    }

    // weights row: 24 floats = 6 x float4 (rows are 96B, 16B-aligned)
    const float4* wrow4 = (const float4*)(weights + (size_t)bi * NJ);
    float wv[NJ];
#pragma unroll
    for (int j = 0; j < 6; ++j) {
        float4 w4 = wrow4[j];
        wv[4*j+0] = w4.x; wv[4*j+1] = w4.y; wv[4*j+2] = w4.z; wv[4*j+3] = w4.w;
    }

    float M1[12], M2[12];
#pragma unroll
    for (int i = 0; i < 12; ++i) { M1[i] = 0.f; M2[i] = 0.f; }
#pragma unroll
    for (int k = 0; k < NJ; ++k) {
        const float w = wv[k];
        const float* a = sAt + k*16;
        const float* b = sAb + k*16;
#pragma unroll
        for (int i = 0; i < 12; ++i) {
            M1[i] = fmaf(w, a[i], M1[i]);
            M2[i] = fmaf(w, b[i], M2[i]);
        }
    }

    // can = inv(M1[:3,:3]) @ (q - M1[:,3])  via adjugate/det (well-conditioned)
    float p0 = q0 - M1[3], p1 = q1 - M1[7], p2 = q2 - M1[11];
    float a_=M1[0], b_=M1[1], c_=M1[2];
    float d_=M1[4], e_=M1[5], f_=M1[6];
    float g_=M1[8], h_=M1[9], i_=M1[10];
    float A0 = e_*i_ - f_*h_, A1 = c_*h_ - b_*i_, A2 = b_*f_ - c_*e_;
    float A3 = f_*g_ - d_*i_, A4 = a_*i_ - c_*g_, A5 = c_*d_ - a_*f_;
    float A6 = d_*h_ - e_*g_, A7 = b_*g_ - a_*h_, A8 = a_*e_ - b_*d_;
    float det  = a_*A0 + b_*A3 + c_*A6;
    float rdet = 1.0f / det;
    float x0 = (A0*p0 + A1*p1 + A2*p2) * rdet;
    float x1 = (A3*p0 + A4*p1 + A5*p2) * rdet;
    float x2 = (A6*p0 + A7*p1 + A8*p2) * rdet;

    // out = M2[:3,:3] @ can + M2[:,3]
    out[3*n+0] = fmaf(M2[0],x0, fmaf(M2[1],x1, fmaf(M2[2], x2, M2[3])));
    out[3*n+1] = fmaf(M2[4],x0, fmaf(M2[5],x1, fmaf(M2[6], x2, M2[7])));
    out[3*n+2] = fmaf(M2[8],x0, fmaf(M2[9],x1, fmaf(M2[10],x2, M2[11])));
}

extern "C" void kernel_launch(void* const* d_in, const int* in_sizes, int n_in,
                              void* d_out, int out_size, void* d_ws, size_t ws_size,
                              hipStream_t stream) {
    const float* qpts    = (const float*)d_in[0];
    const float* verts   = (const float*)d_in[1];
    const float* weights = (const float*)d_in[2];
    const float* At      = (const float*)d_in[3];
    const float* Ab      = (const float*)d_in[4];
    float* out = (float*)d_out;

    const size_t vp_bytes   = (size_t)NVP * sizeof(float4);
    const size_t best_bytes = (size_t)NCHUNK * NPTS * sizeof(float);
    const size_t idx_bytes  = (size_t)NCHUNK * NPTS * sizeof(int);
    const size_t need = vp_bytes + best_bytes + idx_bytes;
    if (ws_size >= need) {
        float4* vp   = (float4*)d_ws;
        float* bestp = (float*)((char*)d_ws + vp_bytes);
        int*   idxp  = (int*)((char*)d_ws + vp_bytes + best_bytes);
        pack_verts_kernel<<<(NVP + 255) / 256, 256, 0, stream>>>(verts, vp);
        knn_kernel<<<NWG, WGS, 0, stream>>>(qpts, vp, bestp, idxp);
        blend_kernel<1><<<NPTS / 256, 256, 0, stream>>>(qpts, verts, weights, At, Ab, bestp, idxp, out);
    } else {
        blend_kernel<0><<<NPTS / 256, 256, 0, stream>>>(qpts, verts, weights, At, Ab, nullptr, nullptr, out);
    }
}

// Round 13
// 277.586 us; speedup vs baseline: 1.6604x; 1.1380x over previous
//
#include <hip/hip_runtime.h>

#define NPTS    262144
#define NV      6890
#define NCHUNK  8
#define CHUNKV  864                  // verts per chunk; 8*864 = 6912
#define NVP     (NCHUNK * CHUNKV)
#define NJ      24
#define PPL     8                    // points per lane
#define WGS     256
#define NPG     (NPTS / (WGS * PPL)) // 128 point-groups
#define NWG     (NPG * NCHUNK)       // 1024 WGs = 4 per CU

// Pack verts as [-2x, -2y, -2z, |v|^2]: d~ = |v|^2 - 2 q.v (argmin-equivalent).
// |v|^2 in numpy's rounding order: (x*x + y*y) + z*z.
__global__ void pack_verts_kernel(const float* __restrict__ verts, float4* __restrict__ vp) {
    int v = blockIdx.x * 256 + threadIdx.x;
    if (v >= NVP) return;
    if (v < NV) {
        float x = verts[3*v+0], y = verts[3*v+1], z = verts[3*v+2];
        float vs = __fadd_rn(__fadd_rn(__fmul_rn(x,x), __fmul_rn(y,y)), __fmul_rn(z,z));
        vp[v] = make_float4(-2.f*x, -2.f*y, -2.f*z, vs);
    } else {
        vp[v] = make_float4(0.f, 0.f, 0.f, 3.0e37f);  // pad: never selected
    }
}

// Kernel A: split-K KNN, PPL=8, forced-minimal argmin update via inline asm:
// per vert: 1 ds_read + 1 v_mov(cand) + 8 x (3 v_fma + v_cmp + 2 v_cndmask).
// Stores u16 LOCAL argmin index per chunk (exact distances recomputed in B).
__global__ __launch_bounds__(WGS, 4)
void knn_kernel(const float* __restrict__ qpts,
                const float4* __restrict__ vp,
                unsigned short* __restrict__ idxp)
{
    __shared__ float4 sv[CHUNKV];
    const int tid   = threadIdx.x;
    const int wg    = blockIdx.x;
    const int chunk = wg & (NCHUNK - 1);
    const int pg    = wg >> 3;
    const int vbase = chunk * CHUNKV;
    const int n0    = pg * (WGS * PPL) + tid;

    for (int i = tid; i < CHUNKV; i += WGS)
        sv[i] = vp[vbase + i];

    float q0[PPL], q1[PPL], q2[PPL];
#pragma unroll
    for (int p = 0; p < PPL; ++p) {
        const int n = n0 + p * WGS;            // coalesced
        q0[p] = qpts[3*n+0]; q1[p] = qpts[3*n+1]; q2[p] = qpts[3*n+2];
    }
    float best[PPL]; int bi[PPL];
#pragma unroll
    for (int p = 0; p < PPL; ++p) { best[p] = 3.4e38f; bi[p] = 0; }

    __syncthreads();

#pragma unroll 8
    for (int u = 0; u < CHUNKV; ++u) {
        const float4 vv = sv[u];               // wave-uniform -> broadcast
        int cand = u;                          // uniform; "v" constraint -> one v_mov
#pragma unroll
        for (int p = 0; p < PPL; ++p) {
            const float d = fmaf(vv.x, q0[p], fmaf(vv.y, q1[p], fmaf(vv.z, q2[p], vv.w)));
            // best = (d<best)?d:best ; bi = (d<best)?cand:bi  -- strict <, first occurrence
            asm("v_cmp_lt_f32 vcc, %2, %0\n\t"
                "v_cndmask_b32 %0, %0, %2, vcc\n\t"
                "v_cndmask_b32 %1, %1, %3, vcc"
                : "+v"(best[p]), "+v"(bi[p])
                : "v"(d), "v"(cand)
                : "vcc");
        }
    }

#pragma unroll
    for (int p = 0; p < PPL; ++p)
        idxp[(size_t)chunk * NPTS + n0 + p * WGS] = (unsigned short)bi[p];
}

// Kernel B: merge 8 chunk-candidates (exact recompute, bit-identical chain),
// then blend/inverse/transform epilogue at full occupancy.
template<int HAVE_IDX>
__global__ __launch_bounds__(256)
void blend_kernel(const float* __restrict__ qpts,
                  const float* __restrict__ verts,
                  const float* __restrict__ weights,
                  const float* __restrict__ At,
                  const float* __restrict__ Ab,
                  const unsigned short* __restrict__ idxp,
                  const float4* __restrict__ vp,
                  float* __restrict__ out)
{
    __shared__ float sAt[NJ*16];
    __shared__ float sAb[NJ*16];
    const int tid = threadIdx.x;
    for (int i = tid; i < NJ*16; i += 256) { sAt[i] = At[i]; sAb[i] = Ab[i]; }

    const int n = blockIdx.x * 256 + tid;
    const float q0 = qpts[3*n+0], q1 = qpts[3*n+1], q2 = qpts[3*n+2];

    int bi;
    if (HAVE_IDX) {
        // candidates are per-chunk winners; recomputed d is bit-identical to
        // kernel A's (same packed vp, same fma chain). Ascending chunk order +
        // strict < preserves numpy first-occurrence tie semantics.
        float bb = 3.4e38f; bi = 0;
#pragma unroll
        for (int c = 0; c < NCHUNK; ++c) {
            const int loc = idxp[(size_t)c * NPTS + n];
            const int gi  = c * CHUNKV + loc;
            const float4 vv = vp[gi];
            const float d = fmaf(vv.x, q0, fmaf(vv.y, q1, fmaf(vv.z, q2, vv.w)));
            const bool lt = d < bb;
            bb = lt ? d : bb;
            bi = lt ? gi : bi;
        }
        __syncthreads();
    } else {
        // fallback: direct scan, reference-shaped rounding
        const float qsq = __fadd_rn(__fadd_rn(__fmul_rn(q0,q0), __fmul_rn(q1,q1)), __fmul_rn(q2,q2));
        float bbest = 3.4e38f; bi = 0;
        for (int v = 0; v < NV; ++v) {
            float vx = verts[3*v+0], vy = verts[3*v+1], vz = verts[3*v+2];
            float vs = __fadd_rn(__fadd_rn(__fmul_rn(vx,vx), __fmul_rn(vy,vy)), __fmul_rn(vz,vz));
            float tq = fmaf(q2, vz, fmaf(q1, vy, __fmul_rn(q0, vx)));
            float d  = __fadd_rn(__fsub_rn(qsq, __fadd_rn(tq, tq)), vs);
            bool lt = d < bbest;
            bbest = lt ? d : bbest;
            bi    = lt ? v : bi;
        }
        __syncthreads();
    }

    // weights row: 24 floats = 6 x float4 (rows are 96B, 16B-aligned)
    const float4* wrow4 = (const float4*)(weights + (size_t)bi * NJ);
    float wv[NJ];
#pragma unroll
    for (int j = 0; j < 6; ++j) {
        float4 w4 = wrow4[j];
        wv[4*j+0] = w4.x; wv[4*j+1] = w4.y; wv[4*j+2] = w4.z; wv[4*j+3] = w4.w;
    }

    float M1[12], M2[12];
#pragma unroll
    for (int i = 0; i < 12; ++i) { M1[i] = 0.f; M2[i] = 0.f; }
#pragma unroll
    for (int k = 0; k < NJ; ++k) {
        const float w = wv[k];
        const float* a = sAt + k*16;
        const float* b = sAb + k*16;
#pragma unroll
        for (int i = 0; i < 12; ++i) {
            M1[i] = fmaf(w, a[i], M1[i]);
            M2[i] = fmaf(w, b[i], M2[i]);
        }
    }

    // can = inv(M1[:3,:3]) @ (q - M1[:,3])  via adjugate/det (well-conditioned)
    float p0 = q0 - M1[3], p1 = q1 - M1[7], p2 = q2 - M1[11];
    float a_=M1[0], b_=M1[1], c_=M1[2];
    float d_=M1[4], e_=M1[5], f_=M1[6];
    float g_=M1[8], h_=M1[9], i_=M1[10];
    float A0 = e_*i_ - f_*h_, A1 = c_*h_ - b_*i_, A2 = b_*f_ - c_*e_;
    float A3 = f_*g_ - d_*i_, A4 = a_*i_ - c_*g_, A5 = c_*d_ - a_*f_;
    float A6 = d_*h_ - e_*g_, A7 = b_*g_ - a_*h_, A8 = a_*e_ - b_*d_;
    float det  = a_*A0 + b_*A3 + c_*A6;
    float rdet = 1.0f / det;
    float x0 = (A0*p0 + A1*p1 + A2*p2) * rdet;
    float x1 = (A3*p0 + A4*p1 + A5*p2) * rdet;
    float x2 = (A6*p0 + A7*p1 + A8*p2) * rdet;

    // out = M2[:3,:3] @ can + M2[:,3]
    out[3*n+0] = fmaf(M2[0],x0, fmaf(M2[1],x1, fmaf(M2[2], x2, M2[3])));
    out[3*n+1] = fmaf(M2[4],x0, fmaf(M2[5],x1, fmaf(M2[6], x2, M2[7])));
    out[3*n+2] = fmaf(M2[8],x0, fmaf(M2[9],x1, fmaf(M2[10],x2, M2[11])));
}

extern "C" void kernel_launch(void* const* d_in, const int* in_sizes, int n_in,
                              void* d_out, int out_size, void* d_ws, size_t ws_size,
                              hipStream_t stream) {
    const float* qpts    = (const float*)d_in[0];
    const float* verts   = (const float*)d_in[1];
    const float* weights = (const float*)d_in[2];
    const float* At      = (const float*)d_in[3];
    const float* Ab      = (const float*)d_in[4];
    float* out = (float*)d_out;

    const size_t vp_bytes  = (size_t)NVP * sizeof(float4);            // ~110 KB
    const size_t idx_bytes = (size_t)NCHUNK * NPTS * sizeof(unsigned short); // 4 MB
    const size_t need = vp_bytes + idx_bytes;
    if (ws_size >= need) {
        float4* vp = (float4*)d_ws;
        unsigned short* idxp = (unsigned short*)((char*)d_ws + vp_bytes);
        pack_verts_kernel<<<(NVP + 255) / 256, 256, 0, stream>>>(verts, vp);
        knn_kernel<<<NWG, WGS, 0, stream>>>(qpts, vp, idxp);
        blend_kernel<1><<<NPTS / 256, 256, 0, stream>>>(qpts, verts, weights, At, Ab, idxp, vp, out);
    } else {
        blend_kernel<0><<<NPTS / 256, 256, 0, stream>>>(qpts, verts, weights, At, Ab, nullptr, nullptr, out);
    }
}